// Round 1
// baseline (917.275 us; speedup 1.0000x reference)
//
#include <hip/hip_runtime.h>

typedef unsigned short ushort_t;
typedef unsigned int u32;
typedef __attribute__((ext_vector_type(4))) float f32x4;
typedef __attribute__((ext_vector_type(8))) short bf16x8;

// Problem constants
#define T_DIM 8192
#define D_IN 1024
#define D_INTER 512
#define N_ELEM (T_DIM * D_INTER)  // 4194304

// ---------- helpers ----------
__device__ __forceinline__ unsigned short f2b(float f) {
  union { float f; u32 u; } v; v.f = f;
  u32 u = v.u;
  u32 r = (u + 0x7fffu + ((u >> 16) & 1u)) >> 16;
  return (unsigned short)r;
}

__device__ __forceinline__ void g2l16(const void* g, void* l) {
  __builtin_amdgcn_global_load_lds((const __attribute__((address_space(1))) u32*)g,
                                   (__attribute__((address_space(3))) u32*)l, 16, 0, 0);
}

// ---------- kernel 1: casts + zero-init ----------
// segments (float4 units): x 2097152 | wq 131072 | wk 131072 | wv 131072 | wr 65536 | Hzero 1048576
__global__ void prep_kernel(const float4* __restrict__ x,
                            const float4* __restrict__ wq, const float4* __restrict__ wk,
                            const float4* __restrict__ wv, const float4* __restrict__ wr,
                            ushort4* __restrict__ xb,
                            ushort4* __restrict__ wqb, ushort4* __restrict__ wkb,
                            ushort4* __restrict__ wvb, ushort4* __restrict__ wrb,
                            float4* __restrict__ H, float* __restrict__ stats) {
  const int gid = blockIdx.x * 256 + threadIdx.x;
  if (gid == 0) { stats[0] = 0.f; stats[1] = 0.f; }
  const float4* src; ushort4* dst; int idx;
  if (gid < 2097152)      { src = x;  dst = xb;  idx = gid; }
  else if (gid < 2228224) { src = wq; dst = wqb; idx = gid - 2097152; }
  else if (gid < 2359296) { src = wk; dst = wkb; idx = gid - 2228224; }
  else if (gid < 2490368) { src = wv; dst = wvb; idx = gid - 2359296; }
  else if (gid < 2555904) { src = wr; dst = wrb; idx = gid - 2490368; }
  else { H[gid - 2555904] = make_float4(0.f, 0.f, 0.f, 0.f); return; }
  float4 v = src[idx];
  ushort4 o;
  o.x = f2b(v.x); o.y = f2b(v.y); o.z = f2b(v.z); o.w = f2b(v.w);
  dst[idx] = o;
}

// ---------- kernel 2: QKV projections  C = xb @ W^T + b ----------
// M=8192, K=1024, N=512, blockIdx.z in {0:Q,1:K,2:V}. 128x128 tiles, BK=32.
// Outputs in k-packed layout: cell(kg,row) = 8 contiguous k-elems, 16 B.
__global__ void gemm_qkv(const ushort_t* __restrict__ xb,
                         const ushort_t* __restrict__ wqb, const ushort_t* __restrict__ wkb,
                         const ushort_t* __restrict__ wvb,
                         const float* __restrict__ bq, const float* __restrict__ bk,
                         const float* __restrict__ bv,
                         ushort_t* __restrict__ Qp, ushort_t* __restrict__ Kp,
                         ushort_t* __restrict__ Vp) {
  __shared__ ushort_t As[4 * 130 * 8];
  __shared__ ushort_t Bs[4 * 130 * 8];
  const int tid = threadIdx.x, wid = tid >> 6, lane = tid & 63;
  const int l15 = lane & 15, q4 = lane >> 4;
  const int m0 = blockIdx.x * 128, n0 = blockIdx.y * 128;
  const int z = blockIdx.z;
  const ushort_t* wb = (z == 0) ? wqb : (z == 1 ? wkb : wvb);
  const float* bias = (z == 0) ? bq : (z == 1 ? bk : bv);
  const int m0w = (wid >> 1) * 64, n0w = (wid & 1) * 64;

  f32x4 acc[4][4];
#pragma unroll
  for (int a = 0; a < 4; ++a)
#pragma unroll
    for (int b = 0; b < 4; ++b) acc[a][b] = f32x4{0.f, 0.f, 0.f, 0.f};

  for (int kt = 0; kt < 32; ++kt) {
#pragma unroll
    for (int j = 0; j < 4; ++j) {
      const int idx = wid * 4 + j;
      const int kg = (idx >> 1) & 3;
      const int half = idx & 1;
      if (idx < 8)
        g2l16(&xb[(size_t)(m0 + half * 64 + lane) * 1024 + kt * 32 + kg * 8],
              &As[(kg * 130 + half * 64) * 8]);
      else
        g2l16(&wb[(size_t)(n0 + half * 64 + lane) * 1024 + kt * 32 + kg * 8],
              &Bs[(kg * 130 + half * 64) * 8]);
    }
    __syncthreads();
    bf16x8 af[4], bfr[4];
#pragma unroll
    for (int t = 0; t < 4; ++t) {
      af[t]  = *(const bf16x8*)&As[(q4 * 130 + m0w + t * 16 + l15) * 8];
      bfr[t] = *(const bf16x8*)&Bs[(q4 * 130 + n0w + t * 16 + l15) * 8];
    }
#pragma unroll
    for (int mt = 0; mt < 4; ++mt)
#pragma unroll
      for (int nt = 0; nt < 4; ++nt)
        acc[mt][nt] = __builtin_amdgcn_mfma_f32_16x16x32_bf16(af[mt], bfr[nt], acc[mt][nt], 0, 0, 0);
    __syncthreads();
  }

#pragma unroll
  for (int nt = 0; nt < 4; ++nt) {
    const int gcol = n0 + n0w + nt * 16 + l15;
    const float bb = bias[gcol];
#pragma unroll
    for (int mt = 0; mt < 4; ++mt)
#pragma unroll
      for (int i = 0; i < 4; ++i) {
        const int grow = m0 + m0w + mt * 16 + q4 * 4 + i;
        const unsigned short v = f2b(acc[mt][nt][i] + bb);
        if (z == 2)
          Vp[((size_t)(grow >> 3) * 512 + gcol) * 8 + (grow & 7)] = v;   // k = T rows
        else if (z == 1)
          Kp[((size_t)(gcol >> 3) * 8192 + grow) * 8 + (gcol & 7)] = v;  // k = inter
        else
          Qp[((size_t)(gcol >> 3) * 8192 + grow) * 8 + (gcol & 7)] = v;
      }
  }
}

// ---------- kernel 3: fused retention  H += (dg ∘ (Q K^T)) V ----------
// grid (128 row-tiles of 64, 4 K-splits of 2048), 256 threads (4 waves), 2 blocks/CU.
__global__ __launch_bounds__(256, 2) void retention_kernel(
    const ushort_t* __restrict__ Qp, const ushort_t* __restrict__ Kp,
    const ushort_t* __restrict__ Vp, const float* __restrict__ dg,
    float* __restrict__ H) {
  __shared__ ushort_t Ss[8 * 66 * 8];  // k-packed A-layout, kg-stride 66 cells (bank spread)
  const int tid = threadIdx.x;
  const int wid = tid >> 6, lane = tid & 63;
  const int l15 = lane & 15, q4 = lane >> 4;
  const int qrow0 = blockIdx.x * 64;
  const int kbase = blockIdx.y * 2048;
  const int r0w = (wid >> 1) * 32;  // S-phase wave region (32x32)
  const int c0w = (wid & 1) * 32;
  const int c0p = wid * 128;        // PV-phase wave columns

  f32x4 hacc[4][8];
#pragma unroll
  for (int a = 0; a < 4; ++a)
#pragma unroll
    for (int b = 0; b < 8; ++b) hacc[a][b] = f32x4{0.f, 0.f, 0.f, 0.f};

  for (int it = 0; it < 32; ++it) {
    const int kt0 = kbase + it * 64;

    // prefetch d_gamma (independent of MFMA chain)
    float gv[16];
#pragma unroll
    for (int mt = 0; mt < 2; ++mt)
#pragma unroll
      for (int nt = 0; nt < 2; ++nt)
#pragma unroll
        for (int i = 0; i < 4; ++i) {
          const int row = r0w + mt * 16 + q4 * 4 + i;
          const int col = c0w + nt * 16 + l15;
          gv[(mt * 2 + nt) * 4 + i] = dg[(size_t)(qrow0 + row) * 8192 + (kt0 + col)];
        }

    // S = Q @ K^T for this wave's 32x32 region
    f32x4 sacc[2][2];
#pragma unroll
    for (int a = 0; a < 2; ++a)
#pragma unroll
      for (int b = 0; b < 2; ++b) sacc[a][b] = f32x4{0.f, 0.f, 0.f, 0.f};

#pragma unroll 4
    for (int ks = 0; ks < 16; ++ks) {
      const int kg = ks * 4 + q4;
      bf16x8 a0 = *(const bf16x8*)&Qp[((size_t)kg * 8192 + qrow0 + r0w + l15) * 8];
      bf16x8 a1 = *(const bf16x8*)&Qp[((size_t)kg * 8192 + qrow0 + r0w + 16 + l15) * 8];
      bf16x8 b0 = *(const bf16x8*)&Kp[((size_t)kg * 8192 + kt0 + c0w + l15) * 8];
      bf16x8 b1 = *(const bf16x8*)&Kp[((size_t)kg * 8192 + kt0 + c0w + 16 + l15) * 8];
      sacc[0][0] = __builtin_amdgcn_mfma_f32_16x16x32_bf16(a0, b0, sacc[0][0], 0, 0, 0);
      sacc[0][1] = __builtin_amdgcn_mfma_f32_16x16x32_bf16(a0, b1, sacc[0][1], 0, 0, 0);
      sacc[1][0] = __builtin_amdgcn_mfma_f32_16x16x32_bf16(a1, b0, sacc[1][0], 0, 0, 0);
      sacc[1][1] = __builtin_amdgcn_mfma_f32_16x16x32_bf16(a1, b1, sacc[1][1], 0, 0, 0);
    }

    // P = dg * S -> bf16 -> Ss (C-layout -> k-packed A-layout via LDS)
#pragma unroll
    for (int mt = 0; mt < 2; ++mt)
#pragma unroll
      for (int nt = 0; nt < 2; ++nt)
#pragma unroll
        for (int i = 0; i < 4; ++i) {
          const int row = r0w + mt * 16 + q4 * 4 + i;
          const int col = c0w + nt * 16 + l15;
          const float v = sacc[mt][nt][i] * gv[(mt * 2 + nt) * 4 + i];
          Ss[((col >> 3) * 66 + row) * 8 + (col & 7)] = f2b(v);
        }
    __syncthreads();

    // H += P @ V  (this wave: all 64 rows x cols [c0p, c0p+128))
#pragma unroll
    for (int ks = 0; ks < 2; ++ks) {
      bf16x8 sa[4];
#pragma unroll
      for (int mt = 0; mt < 4; ++mt)
        sa[mt] = *(const bf16x8*)&Ss[((ks * 4 + q4) * 66 + mt * 16 + l15) * 8];
      const int tg0 = (kt0 >> 3) + ks * 4 + q4;
#pragma unroll
      for (int nt = 0; nt < 8; ++nt) {
        bf16x8 vb = *(const bf16x8*)&Vp[((size_t)tg0 * 512 + c0p + nt * 16 + l15) * 8];
#pragma unroll
        for (int mt = 0; mt < 4; ++mt)
          hacc[mt][nt] = __builtin_amdgcn_mfma_f32_16x16x32_bf16(sa[mt], vb, hacc[mt][nt], 0, 0, 0);
      }
    }
    __syncthreads();
  }

#pragma unroll
  for (int mt = 0; mt < 4; ++mt)
#pragma unroll
    for (int nt = 0; nt < 8; ++nt)
#pragma unroll
      for (int i = 0; i < 4; ++i) {
        const int row = qrow0 + mt * 16 + q4 * 4 + i;
        const int col = c0p + nt * 16 + l15;
        unsafeAtomicAdd(&H[(size_t)row * 512 + col], hacc[mt][nt][i]);
      }
}

// ---------- kernel 4: global sum / sumsq ----------
__global__ void stats_kernel(const float4* __restrict__ H, float* __restrict__ stats) {
  const int tid = blockIdx.x * 256 + threadIdx.x;  // 262144 threads, 4 float4 each
  float s = 0.f, ss = 0.f;
#pragma unroll
  for (int i = 0; i < 4; ++i) {
    float4 v = H[tid + i * 262144];
    s += v.x + v.y + v.z + v.w;
    ss += v.x * v.x + v.y * v.y + v.z * v.z + v.w * v.w;
  }
  for (int off = 32; off; off >>= 1) {
    s += __shfl_down(s, off);
    ss += __shfl_down(ss, off);
  }
  if ((threadIdx.x & 63) == 0) {
    unsafeAtomicAdd(&stats[0], s);
    unsafeAtomicAdd(&stats[1], ss);
  }
}

// ---------- kernel 5: GroupNorm normalize + bf16 cast ----------
__global__ void norm_kernel(const float4* __restrict__ H, const float* __restrict__ stats,
                            const float* __restrict__ gnw, const float* __restrict__ gnb,
                            ushort4* __restrict__ hnb) {
  const int gid = blockIdx.x * 256 + threadIdx.x;  // 1048576 float4
  const float inv_n = 1.f / (float)N_ELEM;
  const float mean = stats[0] * inv_n;
  const float var = stats[1] * inv_n - mean * mean;
  const float rstd = rsqrtf(var + 1e-5f);
  float4 h = H[gid];
  const int c0 = (gid * 4) & 511;
  const float4 w = *(const float4*)&gnw[c0];
  const float4 b = *(const float4*)&gnb[c0];
  ushort4 o;
  o.x = f2b((h.x - mean) * rstd * w.x + b.x);
  o.y = f2b((h.y - mean) * rstd * w.y + b.y);
  o.z = f2b((h.z - mean) * rstd * w.z + b.z);
  o.w = f2b((h.w - mean) * rstd * w.w + b.w);
  hnb[gid] = o;
}

// ---------- kernel 6: output projection + PReLU ----------
// y = hn @ Wr^T + br ; PReLU. M=8192, K=512, N=512.
__global__ void gemm_out(const ushort_t* __restrict__ hnb, const ushort_t* __restrict__ wrb,
                         const float* __restrict__ br, const float* __restrict__ prelu,
                         float* __restrict__ out) {
  __shared__ ushort_t As[4 * 130 * 8];
  __shared__ ushort_t Bs[4 * 130 * 8];
  const int tid = threadIdx.x, wid = tid >> 6, lane = tid & 63;
  const int l15 = lane & 15, q4 = lane >> 4;
  const int m0 = blockIdx.x * 128, n0 = blockIdx.y * 128;
  const int m0w = (wid >> 1) * 64, n0w = (wid & 1) * 64;

  f32x4 acc[4][4];
#pragma unroll
  for (int a = 0; a < 4; ++a)
#pragma unroll
    for (int b = 0; b < 4; ++b) acc[a][b] = f32x4{0.f, 0.f, 0.f, 0.f};

  for (int kt = 0; kt < 16; ++kt) {
#pragma unroll
    for (int j = 0; j < 4; ++j) {
      const int idx = wid * 4 + j;
      const int kg = (idx >> 1) & 3;
      const int half = idx & 1;
      if (idx < 8)
        g2l16(&hnb[(size_t)(m0 + half * 64 + lane) * 512 + kt * 32 + kg * 8],
              &As[(kg * 130 + half * 64) * 8]);
      else
        g2l16(&wrb[(size_t)(n0 + half * 64 + lane) * 512 + kt * 32 + kg * 8],
              &Bs[(kg * 130 + half * 64) * 8]);
    }
    __syncthreads();
    bf16x8 af[4], bfr[4];
#pragma unroll
    for (int t = 0; t < 4; ++t) {
      af[t]  = *(const bf16x8*)&As[(q4 * 130 + m0w + t * 16 + l15) * 8];
      bfr[t] = *(const bf16x8*)&Bs[(q4 * 130 + n0w + t * 16 + l15) * 8];
    }
#pragma unroll
    for (int mt = 0; mt < 4; ++mt)
#pragma unroll
      for (int nt = 0; nt < 4; ++nt)
        acc[mt][nt] = __builtin_amdgcn_mfma_f32_16x16x32_bf16(af[mt], bfr[nt], acc[mt][nt], 0, 0, 0);
    __syncthreads();
  }

  const float slope = prelu[0];
#pragma unroll
  for (int nt = 0; nt < 4; ++nt) {
    const int gcol = n0 + n0w + nt * 16 + l15;
    const float bb = br[gcol];
#pragma unroll
    for (int mt = 0; mt < 4; ++mt)
#pragma unroll
      for (int i = 0; i < 4; ++i) {
        const int grow = m0 + m0w + mt * 16 + q4 * 4 + i;
        float v = acc[mt][nt][i] + bb;
        v = (v >= 0.f) ? v : v * slope;
        out[(size_t)grow * 512 + gcol] = v;
      }
  }
}

// ---------- workspace layout (bytes) ----------
#define OFF_XB  0ULL          // 16777216
#define OFF_WQB 16777216ULL   // 1048576
#define OFF_WKB 17825792ULL
#define OFF_WVB 18874368ULL
#define OFF_WRB 19922944ULL   // 524288
#define OFF_QP  20447232ULL   // 8388608
#define OFF_KP  28835840ULL
#define OFF_VP  37224448ULL
#define OFF_H   45613056ULL   // 16777216
#define OFF_HNB 62390272ULL   // 8388608
#define OFF_ST  70778880ULL   // small

extern "C" void kernel_launch(void* const* d_in, const int* in_sizes, int n_in,
                              void* d_out, int out_size, void* d_ws, size_t ws_size,
                              hipStream_t stream) {
  const float* x     = (const float*)d_in[0];
  const float* dg    = (const float*)d_in[1];
  const float* Wq    = (const float*)d_in[2];
  const float* bq    = (const float*)d_in[3];
  const float* Wk    = (const float*)d_in[4];
  const float* bk    = (const float*)d_in[5];
  const float* Wv    = (const float*)d_in[6];
  const float* bv    = (const float*)d_in[7];
  const float* Wr    = (const float*)d_in[8];
  const float* br    = (const float*)d_in[9];
  const float* gnw   = (const float*)d_in[10];
  const float* gnb   = (const float*)d_in[11];
  const float* prelu = (const float*)d_in[12];
  float* out = (float*)d_out;
  char* ws = (char*)d_ws;

  ushort_t* xb  = (ushort_t*)(ws + OFF_XB);
  ushort_t* wqb = (ushort_t*)(ws + OFF_WQB);
  ushort_t* wkb = (ushort_t*)(ws + OFF_WKB);
  ushort_t* wvb = (ushort_t*)(ws + OFF_WVB);
  ushort_t* wrb = (ushort_t*)(ws + OFF_WRB);
  ushort_t* Qp  = (ushort_t*)(ws + OFF_QP);
  ushort_t* Kp  = (ushort_t*)(ws + OFF_KP);
  ushort_t* Vp  = (ushort_t*)(ws + OFF_VP);
  float* H      = (float*)(ws + OFF_H);
  ushort_t* hnb = (ushort_t*)(ws + OFF_HNB);
  float* stats  = (float*)(ws + OFF_ST);

  prep_kernel<<<14080, 256, 0, stream>>>(
      (const float4*)x, (const float4*)Wq, (const float4*)Wk, (const float4*)Wv,
      (const float4*)Wr, (ushort4*)xb, (ushort4*)wqb, (ushort4*)wkb, (ushort4*)wvb,
      (ushort4*)wrb, (float4*)H, stats);

  gemm_qkv<<<dim3(64, 4, 3), 256, 0, stream>>>(xb, wqb, wkb, wvb, bq, bk, bv, Qp, Kp, Vp);

  retention_kernel<<<dim3(128, 4), 256, 0, stream>>>(Qp, Kp, Vp, dg, H);

  stats_kernel<<<1024, 256, 0, stream>>>((const float4*)H, stats);

  norm_kernel<<<4096, 256, 0, stream>>>((const float4*)H, stats, gnw, gnb, (ushort4*)hnb);

  gemm_out<<<dim3(64, 4), 256, 0, stream>>>(hnb, wrb, br, prelu, out);
}